// Round 1
// baseline (302.380 us; speedup 1.0000x reference)
//
#include <hip/hip_runtime.h>
#include <hip/hip_bf16.h>

typedef __bf16 bf16x8 __attribute__((ext_vector_type(8)));
typedef float f32x4 __attribute__((ext_vector_type(4)));

#define EPSBN 1e-3f

constexpr int NPIX = 4096;   // H*W
constexpr int D2 = 256;      // C/2

// ---------- x -> bf16 ----------
__global__ __launch_bounds__(256) void k_cvt(const float* __restrict__ x,
                                             __bf16* __restrict__ xb, int n4) {
  int i = blockIdx.x * 256 + threadIdx.x;
  if (i >= n4) return;
  float4 v = reinterpret_cast<const float4*>(x)[i];
  union { __bf16 h[4]; uint2 u; } o;
  o.h[0] = (__bf16)v.x; o.h[1] = (__bf16)v.y; o.h[2] = (__bf16)v.z; o.h[3] = (__bf16)v.w;
  reinterpret_cast<uint2*>(xb)[i] = o.u;
}

// ---------- weight precompute ----------
// WfghT[c][k], c<64:f  64..127:g  128..383:hv   (384 x 512, bf16)
__global__ __launch_bounds__(256) void kp_wfgh(const float* __restrict__ wf,
                                               const float* __restrict__ wg,
                                               const float* __restrict__ wh,
                                               __bf16* __restrict__ WT) {
  int idx = blockIdx.x * 256 + threadIdx.x;  // < 384*512
  int c = idx >> 9, k = idx & 511;
  float v = (c < 64) ? wf[k * 64 + c] : (c < 128) ? wg[k * 64 + (c - 64)] : wh[k * 256 + (c - 128)];
  WT[idx] = (__bf16)v;
}

__global__ __launch_bounds__(128) void kp_bias384(const float* bf_, const float* bg_,
                                                  const float* bh_, float* bias) {
  int c = blockIdx.x * 128 + threadIdx.x;  // grid 3 -> 384
  bias[c] = (c < 64) ? bf_[c] : (c < 128) ? bg_[c - 64] : bh_[c - 128];
}

// Wow[d][c] = sum_j wo[d][j] * wc[j][c]   (256 x 512, fp32)
__global__ __launch_bounds__(256) void kp_wow(const float* __restrict__ wo,
                                              const float* __restrict__ wc,
                                              float* __restrict__ Wow) {
  int idx = blockIdx.x * 256 + threadIdx.x;  // 256*512
  int d = idx >> 9, c = idx & 511;
  float acc = 0.f;
  for (int j = 0; j < 512; ++j) acc += wo[d * 512 + j] * wc[j * 512 + c];
  Wow[idx] = acc;
}

// WcatT[c][k]  (512 x 768, bf16): k<256 -> gamma*Wow[k][c]*s[c] ; k>=256 -> (wc_top+wc_bot)[k-256][c]*s[c]
__global__ __launch_bounds__(256) void kp_wcat(const float* __restrict__ Wow,
                                               const float* __restrict__ wc,
                                               const float* __restrict__ gamma,
                                               const float* __restrict__ bns,
                                               const float* __restrict__ bnv,
                                               __bf16* __restrict__ WT) {
  int idx = blockIdx.x * 256 + threadIdx.x;  // 512*768
  int c = idx / 768, k = idx % 768;
  float s = bns[c] * rsqrtf(bnv[c] + EPSBN);
  float v;
  if (k < 256) v = gamma[0] * Wow[k * 512 + c] * s;
  else { int kk = k - 256; v = (wc[kk * 512 + c] + wc[(512 + kk) * 512 + c]) * s; }
  WT[idx] = (__bf16)v;
}

// biasF[c] = (bc[c] + gamma*sum_j bo[j]*wc[j][c] - mean[c])*s[c] + bnb[c]
__global__ __launch_bounds__(256) void kp_biasF(const float* bo, const float* wc, const float* bc,
                                                const float* gamma, const float* bns, const float* bnb,
                                                const float* bnm, const float* bnv, float* biasF) {
  int c = blockIdx.x * 256 + threadIdx.x;  // grid 2 -> 512
  float s = bns[c] * rsqrtf(bnv[c] + EPSBN);
  float acc = 0.f;
  for (int j = 0; j < 512; ++j) acc += bo[j] * wc[j * 512 + c];
  float pre = bc[c] + gamma[0] * acc;
  biasF[c] = (pre - bnm[c]) * s + bnb[c];
}

// ---------- generic MFMA GEMM: C[M][NC] = A[M][KT] @ WT^T + bias ----------
// A split in two row-sources (k < k1 from A1, else A2). WT is [NC][KT] row-major (= W^T).
template <int KT, int NC, bool FINAL>
__global__ __launch_bounds__(256) void k_gemm(const __bf16* __restrict__ A1, int k1, int lda1,
                                              const __bf16* __restrict__ A2, int lda2,
                                              const __bf16* __restrict__ WT,
                                              const float* __restrict__ bias,
                                              void* __restrict__ outp) {
  __shared__ __bf16 As[128][72];
  __shared__ __bf16 Ws[64][72];
  const int m0 = blockIdx.x * 128, n0 = blockIdx.y * 64;
  const int tid = threadIdx.x, lane = tid & 63, w = tid >> 6;
  const int wr = w >> 1, wcl = w & 1;
  const int l15 = lane & 15, l4 = lane >> 4;
  f32x4 acc[4][2] = {};
  for (int ks = 0; ks < KT; ks += 64) {
    const __bf16* Asrc; int lda, kb;
    if (ks < k1) { Asrc = A1; lda = lda1; kb = ks; }
    else         { Asrc = A2; lda = lda2; kb = ks - k1; }
#pragma unroll
    for (int it = 0; it < 4; ++it) {
      int idx = it * 256 + tid, r = idx >> 3, ch = idx & 7;
      *(bf16x8*)(&As[r][ch * 8]) = *(const bf16x8*)(Asrc + (size_t)(m0 + r) * lda + kb + ch * 8);
    }
#pragma unroll
    for (int it = 0; it < 2; ++it) {
      int idx = it * 256 + tid, r = idx >> 3, ch = idx & 7;
      *(bf16x8*)(&Ws[r][ch * 8]) = *(const bf16x8*)(WT + (size_t)(n0 + r) * KT + ks + ch * 8);
    }
    __syncthreads();
#pragma unroll
    for (int kk = 0; kk < 2; ++kk) {
      int krd = kk * 32 + l4 * 8;
      bf16x8 av[4], bv[2];
#pragma unroll
      for (int mi = 0; mi < 4; ++mi) av[mi] = *(const bf16x8*)(&As[wr * 64 + mi * 16 + l15][krd]);
#pragma unroll
      for (int ni = 0; ni < 2; ++ni) bv[ni] = *(const bf16x8*)(&Ws[wcl * 32 + ni * 16 + l15][krd]);
#pragma unroll
      for (int mi = 0; mi < 4; ++mi)
#pragma unroll
        for (int ni = 0; ni < 2; ++ni)
          acc[mi][ni] = __builtin_amdgcn_mfma_f32_16x16x32_bf16(av[mi], bv[ni], acc[mi][ni], 0, 0, 0);
    }
    __syncthreads();
  }
#pragma unroll
  for (int mi = 0; mi < 4; ++mi)
#pragma unroll
    for (int ni = 0; ni < 2; ++ni) {
      int col = n0 + wcl * 32 + ni * 16 + l15;
      float bcol = bias[col];
#pragma unroll
      for (int r = 0; r < 4; ++r) {
        int row = m0 + wr * 64 + mi * 16 + l4 * 4 + r;
        float v = acc[mi][ni][r] + bcol;
        if (FINAL) ((float*)outp)[(size_t)row * NC + col] = fmaxf(v, 0.f);
        else ((__bf16*)outp)[(size_t)row * NC + col] = (__bf16)v;
      }
    }
}

// ---------- hv transpose: hvT[b][d][n] = fgh[b][n][128+d] ----------
__global__ __launch_bounds__(256) void k_trans(const __bf16* __restrict__ fgh,
                                               __bf16* __restrict__ hvT) {
  __shared__ __bf16 T[64][72];
  int b = blockIdx.z, n0 = blockIdx.x * 64, d0 = blockIdx.y * 64;
  int tid = threadIdx.x;
  const __bf16* src = fgh + (size_t)b * NPIX * 384;
#pragma unroll
  for (int it = 0; it < 2; ++it) {
    int idx = it * 256 + tid, r = idx >> 3, ch = idx & 7;
    *(bf16x8*)(&T[r][ch * 8]) = *(const bf16x8*)(src + (size_t)(n0 + r) * 384 + 128 + d0 + ch * 8);
  }
  __syncthreads();
  __bf16* dst = hvT + ((size_t)b * D2 + d0) * NPIX + n0;
#pragma unroll
  for (int it = 0; it < 2; ++it) {
    int idx = it * 256 + tid, r = idx >> 3, ch = idx & 7;
    bf16x8 v;
#pragma unroll
    for (int j = 0; j < 8; ++j) v[j] = T[ch * 8 + j][r];
    *(bf16x8*)(dst + (size_t)r * NPIX + ch * 8) = v;
  }
}

// ---------- attention: o[b][q][d] = softmax_m(g·f^T)[q][m] @ hv[m][d] ----------
// no-max softmax: p = exp(s) (safe: |s| << 87), denom reduced at end
__global__ __launch_bounds__(256, 2) void k_attn(const __bf16* __restrict__ fgh,
                                                 const __bf16* __restrict__ hvT,
                                                 __bf16* __restrict__ obuf) {
  __shared__ __bf16 Fs[64][72];
  __shared__ __bf16 Vs[256][72];
  __shared__ __bf16 Ps[32][72];
  __shared__ float Lp[4][32];
  const int b = blockIdx.y, q0 = blockIdx.x * 32;
  const int tid = threadIdx.x, w = tid >> 6, lane = tid & 63;
  const int l15 = lane & 15, l4 = lane >> 4;
  const __bf16* base = fgh + (size_t)b * NPIX * 384;
  const __bf16* vbase = hvT + (size_t)b * D2 * NPIX;
  bf16x8 aG[2][2];
#pragma unroll
  for (int qi = 0; qi < 2; ++qi)
#pragma unroll
    for (int kk = 0; kk < 2; ++kk)
      aG[qi][kk] = *(const bf16x8*)(base + (size_t)(q0 + qi * 16 + l15) * 384 + 64 + kk * 32 + l4 * 8);
  f32x4 accO[2][4] = {};
  f32x4 lsum[2] = {};
  for (int m0 = 0; m0 < NPIX; m0 += 64) {
#pragma unroll
    for (int it = 0; it < 2; ++it) {  // F tile [64][64] (f = cols 0..63 of fgh)
      int idx = it * 256 + tid, r = idx >> 3, ch = idx & 7;
      *(bf16x8*)(&Fs[r][ch * 8]) = *(const bf16x8*)(base + (size_t)(m0 + r) * 384 + ch * 8);
    }
#pragma unroll
    for (int it = 0; it < 8; ++it) {  // V^T tile [256][64]
      int idx = it * 256 + tid, r = idx >> 3, ch = idx & 7;
      *(bf16x8*)(&Vs[r][ch * 8]) = *(const bf16x8*)(vbase + (size_t)r * NPIX + m0 + ch * 8);
    }
    __syncthreads();
    // S tile: wave w computes cols w*16..+16 for all 32 q rows
#pragma unroll
    for (int qi = 0; qi < 2; ++qi) {
      f32x4 sa = {};
#pragma unroll
      for (int kk = 0; kk < 2; ++kk) {
        bf16x8 bF = *(const bf16x8*)(&Fs[w * 16 + l15][kk * 32 + l4 * 8]);
        sa = __builtin_amdgcn_mfma_f32_16x16x32_bf16(aG[qi][kk], bF, sa, 0, 0, 0);
      }
#pragma unroll
      for (int r = 0; r < 4; ++r) {
        float p = __expf(sa[r]);
        lsum[qi][r] += p;
        Ps[qi * 16 + l4 * 4 + r][w * 16 + l15] = (__bf16)p;
      }
    }
    __syncthreads();
    // O += P @ V : wave w owns d cols w*64..+64
#pragma unroll
    for (int kk = 0; kk < 2; ++kk) {
      bf16x8 aP[2];
#pragma unroll
      for (int qi = 0; qi < 2; ++qi) aP[qi] = *(const bf16x8*)(&Ps[qi * 16 + l15][kk * 32 + l4 * 8]);
#pragma unroll
      for (int dj = 0; dj < 4; ++dj) {
        bf16x8 bV = *(const bf16x8*)(&Vs[w * 64 + dj * 16 + l15][kk * 32 + l4 * 8]);
#pragma unroll
        for (int qi = 0; qi < 2; ++qi)
          accO[qi][dj] = __builtin_amdgcn_mfma_f32_16x16x32_bf16(aP[qi], bV, accO[qi][dj], 0, 0, 0);
      }
    }
    __syncthreads();
  }
#pragma unroll
  for (int qi = 0; qi < 2; ++qi)
#pragma unroll
    for (int r = 0; r < 4; ++r) {
      float v = lsum[qi][r];
      v += __shfl_xor(v, 1); v += __shfl_xor(v, 2); v += __shfl_xor(v, 4); v += __shfl_xor(v, 8);
      lsum[qi][r] = v;
    }
  if (l15 == 0) {
#pragma unroll
    for (int qi = 0; qi < 2; ++qi)
#pragma unroll
      for (int r = 0; r < 4; ++r) Lp[w][qi * 16 + l4 * 4 + r] = lsum[qi][r];
  }
  __syncthreads();
  __bf16* out = obuf + ((size_t)b * NPIX + q0) * D2;
#pragma unroll
  for (int qi = 0; qi < 2; ++qi)
#pragma unroll
    for (int r = 0; r < 4; ++r) {
      int q = qi * 16 + l4 * 4 + r;
      float lt = Lp[0][q] + Lp[1][q] + Lp[2][q] + Lp[3][q];
      float inv = 1.0f / lt;
#pragma unroll
      for (int dj = 0; dj < 4; ++dj)
        out[(size_t)q * D2 + w * 64 + dj * 16 + l15] = (__bf16)(accO[qi][dj][r] * inv);
    }
}

// ---------- launch ----------
extern "C" void kernel_launch(void* const* d_in, const int* in_sizes, int n_in,
                              void* d_out, int out_size, void* d_ws, size_t ws_size,
                              hipStream_t stream) {
  const float* x = (const float*)d_in[0];
  const float* wf = (const float*)d_in[1];
  const float* bf_ = (const float*)d_in[2];
  const float* wg = (const float*)d_in[3];
  const float* bg_ = (const float*)d_in[4];
  const float* wh = (const float*)d_in[5];
  const float* bh_ = (const float*)d_in[6];
  const float* wo = (const float*)d_in[7];
  const float* bo = (const float*)d_in[8];
  const float* gamma = (const float*)d_in[9];
  const float* wc = (const float*)d_in[10];
  const float* bc = (const float*)d_in[11];
  const float* bns = (const float*)d_in[12];
  const float* bnb = (const float*)d_in[13];
  const float* bnm = (const float*)d_in[14];
  const float* bnv = (const float*)d_in[15];
  (void)in_sizes; (void)n_in; (void)out_size; (void)ws_size;

  char* ws = (char*)d_ws;
  __bf16* xb     = (__bf16*)(ws + 0);          // 16384*512*2  = 16,777,216
  __bf16* fgh    = (__bf16*)(ws + 16777216);   // 16384*384*2  = 12,582,912
  __bf16* hvT    = (__bf16*)(ws + 29360128);   // 4*256*4096*2 =  8,388,608
  __bf16* obuf   = (__bf16*)(ws + 37748736);   // 16384*256*2  =  8,388,608
  __bf16* WfghT  = (__bf16*)(ws + 46137344);   // 384*512*2
  float*  bias384= (float*) (ws + 46530560);   // 384*4
  float*  Wow    = (float*) (ws + 46532096);   // 256*512*4
  __bf16* WcatT  = (__bf16*)(ws + 47056384);   // 512*768*2
  float*  biasF  = (float*) (ws + 47842816);   // 512*4
  float* out = (float*)d_out;

  hipLaunchKernelGGL(k_cvt, dim3(8192), dim3(256), 0, stream, x, xb, 2097152);
  hipLaunchKernelGGL(kp_wfgh, dim3(768), dim3(256), 0, stream, wf, wg, wh, WfghT);
  hipLaunchKernelGGL(kp_bias384, dim3(3), dim3(128), 0, stream, bf_, bg_, bh_, bias384);
  hipLaunchKernelGGL(kp_wow, dim3(512), dim3(256), 0, stream, wo, wc, Wow);
  hipLaunchKernelGGL(kp_wcat, dim3(1536), dim3(256), 0, stream, Wow, wc, gamma, bns, bnv, WcatT);
  hipLaunchKernelGGL(kp_biasF, dim3(2), dim3(256), 0, stream, bo, wc, bc, gamma, bns, bnb, bnm, bnv, biasF);
  hipLaunchKernelGGL((k_gemm<512, 384, false>), dim3(128, 6), dim3(256), 0, stream,
                     xb, 512, 512, xb, 512, WfghT, bias384, (void*)fgh);
  hipLaunchKernelGGL(k_trans, dim3(64, 4, 4), dim3(256), 0, stream, fgh, hvT);
  hipLaunchKernelGGL(k_attn, dim3(128, 4), dim3(256), 0, stream, fgh, hvT, obuf);
  hipLaunchKernelGGL((k_gemm<768, 512, true>), dim3(128, 8), dim3(256), 0, stream,
                     obuf, 256, 256, xb, 512, WcatT, biasF, (void*)out);
}

// Round 2
// 278.385 us; speedup vs baseline: 1.0862x; 1.0862x over previous
//
#include <hip/hip_runtime.h>
#include <hip/hip_bf16.h>

typedef __bf16 bf16x8 __attribute__((ext_vector_type(8)));
typedef float f32x4 __attribute__((ext_vector_type(4)));

#define EPSBN 1e-3f

constexpr int NPIX = 4096;   // H*W
constexpr int D2 = 256;      // C/2

#define RAW_BARRIER() do { \
  asm volatile("s_waitcnt lgkmcnt(0)" ::: "memory"); \
  __builtin_amdgcn_s_barrier(); \
  asm volatile("" ::: "memory"); \
} while (0)

// ---------- x -> bf16 ----------
__global__ __launch_bounds__(256) void k_cvt(const float* __restrict__ x,
                                             __bf16* __restrict__ xb, int n4) {
  int i = blockIdx.x * 256 + threadIdx.x;
  if (i >= n4) return;
  float4 v = reinterpret_cast<const float4*>(x)[i];
  union { __bf16 h[4]; uint2 u; } o;
  o.h[0] = (__bf16)v.x; o.h[1] = (__bf16)v.y; o.h[2] = (__bf16)v.z; o.h[3] = (__bf16)v.w;
  reinterpret_cast<uint2*>(xb)[i] = o.u;
}

// ---------- weight precompute ----------
__global__ __launch_bounds__(256) void kp_wfgh(const float* __restrict__ wf,
                                               const float* __restrict__ wg,
                                               const float* __restrict__ wh,
                                               __bf16* __restrict__ WT) {
  int idx = blockIdx.x * 256 + threadIdx.x;  // < 384*512
  int c = idx >> 9, k = idx & 511;
  float v = (c < 64) ? wf[k * 64 + c] : (c < 128) ? wg[k * 64 + (c - 64)] : wh[k * 256 + (c - 128)];
  WT[idx] = (__bf16)v;
}

__global__ __launch_bounds__(128) void kp_bias384(const float* bf_, const float* bg_,
                                                  const float* bh_, float* bias) {
  int c = blockIdx.x * 128 + threadIdx.x;  // grid 3 -> 384
  bias[c] = (c < 64) ? bf_[c] : (c < 128) ? bg_[c - 64] : bh_[c - 128];
}

__global__ __launch_bounds__(256) void kp_wow(const float* __restrict__ wo,
                                              const float* __restrict__ wc,
                                              float* __restrict__ Wow) {
  int idx = blockIdx.x * 256 + threadIdx.x;  // 256*512
  int d = idx >> 9, c = idx & 511;
  float acc = 0.f;
  for (int j = 0; j < 512; ++j) acc += wo[d * 512 + j] * wc[j * 512 + c];
  Wow[idx] = acc;
}

__global__ __launch_bounds__(256) void kp_wcat(const float* __restrict__ Wow,
                                               const float* __restrict__ wc,
                                               const float* __restrict__ gamma,
                                               const float* __restrict__ bns,
                                               const float* __restrict__ bnv,
                                               __bf16* __restrict__ WT) {
  int idx = blockIdx.x * 256 + threadIdx.x;  // 512*768
  int c = idx / 768, k = idx % 768;
  float s = bns[c] * rsqrtf(bnv[c] + EPSBN);
  float v;
  if (k < 256) v = gamma[0] * Wow[k * 512 + c] * s;
  else { int kk = k - 256; v = (wc[kk * 512 + c] + wc[(512 + kk) * 512 + c]) * s; }
  WT[idx] = (__bf16)v;
}

__global__ __launch_bounds__(256) void kp_biasF(const float* bo, const float* wc, const float* bc,
                                                const float* gamma, const float* bns, const float* bnb,
                                                const float* bnm, const float* bnv, float* biasF) {
  int c = blockIdx.x * 256 + threadIdx.x;  // grid 2 -> 512
  float s = bns[c] * rsqrtf(bnv[c] + EPSBN);
  float acc = 0.f;
  for (int j = 0; j < 512; ++j) acc += bo[j] * wc[j * 512 + c];
  float pre = bc[c] + gamma[0] * acc;
  biasF[c] = (pre - bnm[c]) * s + bnb[c];
}

// ---------- generic MFMA GEMM: C[M][NC] = A[M][KT] @ WT^T + bias ----------
// MODE 0: out1 = fg [M][128] bf16 (cols<128), out2 = hvT [B][256][4096] bf16 (cols>=128, transposed)
// MODE 1: out1 = float out [M][NC], relu
template <int KT, int NC, int MODE>
__global__ __launch_bounds__(256) void k_gemm(const __bf16* __restrict__ A1, int k1, int lda1,
                                              const __bf16* __restrict__ A2, int lda2,
                                              const __bf16* __restrict__ WT,
                                              const float* __restrict__ bias,
                                              void* __restrict__ out1,
                                              void* __restrict__ out2) {
  __shared__ __bf16 As[128][72];
  __shared__ __bf16 Ws[64][72];
  const int m0 = blockIdx.x * 128, n0 = blockIdx.y * 64;
  const int tid = threadIdx.x, lane = tid & 63, w = tid >> 6;
  const int wr = w >> 1, wcl = w & 1;
  const int l15 = lane & 15, l4 = lane >> 4;
  f32x4 acc[4][2] = {};
  for (int ks = 0; ks < KT; ks += 64) {
    const __bf16* Asrc; int lda, kb;
    if (ks < k1) { Asrc = A1; lda = lda1; kb = ks; }
    else         { Asrc = A2; lda = lda2; kb = ks - k1; }
#pragma unroll
    for (int it = 0; it < 4; ++it) {
      int idx = it * 256 + tid, r = idx >> 3, ch = idx & 7;
      *(bf16x8*)(&As[r][ch * 8]) = *(const bf16x8*)(Asrc + (size_t)(m0 + r) * lda + kb + ch * 8);
    }
#pragma unroll
    for (int it = 0; it < 2; ++it) {
      int idx = it * 256 + tid, r = idx >> 3, ch = idx & 7;
      *(bf16x8*)(&Ws[r][ch * 8]) = *(const bf16x8*)(WT + (size_t)(n0 + r) * KT + ks + ch * 8);
    }
    __syncthreads();
#pragma unroll
    for (int kk = 0; kk < 2; ++kk) {
      int krd = kk * 32 + l4 * 8;
      bf16x8 av[4], bv[2];
#pragma unroll
      for (int mi = 0; mi < 4; ++mi) av[mi] = *(const bf16x8*)(&As[wr * 64 + mi * 16 + l15][krd]);
#pragma unroll
      for (int ni = 0; ni < 2; ++ni) bv[ni] = *(const bf16x8*)(&Ws[wcl * 32 + ni * 16 + l15][krd]);
#pragma unroll
      for (int mi = 0; mi < 4; ++mi)
#pragma unroll
        for (int ni = 0; ni < 2; ++ni)
          acc[mi][ni] = __builtin_amdgcn_mfma_f32_16x16x32_bf16(av[mi], bv[ni], acc[mi][ni], 0, 0, 0);
    }
    __syncthreads();
  }
#pragma unroll
  for (int mi = 0; mi < 4; ++mi)
#pragma unroll
    for (int ni = 0; ni < 2; ++ni) {
      int col = n0 + wcl * 32 + ni * 16 + l15;
      float bcol = bias[col];
      int row0 = m0 + wr * 64 + mi * 16 + l4 * 4;
      if (MODE == 1) {
        float* out = (float*)out1;
#pragma unroll
        for (int r = 0; r < 4; ++r)
          out[(size_t)(row0 + r) * NC + col] = fmaxf(acc[mi][ni][r] + bcol, 0.f);
      } else {
        if (col < 128) {
          __bf16* fg = (__bf16*)out1;
#pragma unroll
          for (int r = 0; r < 4; ++r)
            fg[(size_t)(row0 + r) * 128 + col] = (__bf16)(acc[mi][ni][r] + bcol);
        } else {
          __bf16* hvT = (__bf16*)out2;
          int bb = row0 >> 12, n = row0 & 4095;
          union { __bf16 h[4]; uint2 u; } pk;
#pragma unroll
          for (int r = 0; r < 4; ++r) pk.h[r] = (__bf16)(acc[mi][ni][r] + bcol);
          *(uint2*)(hvT + ((size_t)(bb * 256 + (col - 128))) * 4096 + n) = pk.u;
        }
      }
    }
}

// ---------- attention ----------
// fg: [B*4096][128] (f: cols 0..63 keys, g: cols 64..127 queries), hvT: [B][256][4096]
// Swapped QK^T (S^T = F G^T), no-max softmax p=exp(s), P exchanged via small LDS (dbuf),
// F/V fragments loaded global->reg directly (L2 resident), prefetched 1 iter ahead.
__global__ __launch_bounds__(512, 2) void k_attn(const __bf16* __restrict__ fg,
                                                 const __bf16* __restrict__ hvT,
                                                 __bf16* __restrict__ obuf) {
  __shared__ __bf16 PsT[2][64][136];
  __shared__ float Lp[8][64];
  // XCD swizzle: batch b -> 2 XCDs, so each XCD's L2 caches one batch's F+V (2.5MB < 4MB)
  const int id = blockIdx.x;
  const int xcd = id & 7, i2 = id >> 3;
  const int b = xcd >> 1;
  const int q0 = (i2 * 2 + (xcd & 1)) * 64;
  const int tid = threadIdx.x, w = tid >> 6, lane = tid & 63;
  const int l15 = lane & 15, l4 = lane >> 4;
  const __bf16* fgb = fg + (size_t)b * NPIX * 128;
  const __bf16* vb = hvT + (size_t)b * D2 * NPIX;

  // preload query fragments bG[qt][kk]
  bf16x8 bG[4][2];
#pragma unroll
  for (int qt = 0; qt < 4; ++qt)
#pragma unroll
    for (int kk = 0; kk < 2; ++kk)
      bG[qt][kk] = *(const bf16x8*)(fgb + (size_t)(q0 + qt * 16 + l15) * 128 + 64 + kk * 32 + l4 * 8);

  // prologue prefetch: key fragments (this wave's m-slice) and V fragments (this wave's d-slice)
  bf16x8 aF[2], bV[2][4];
#pragma unroll
  for (int kk = 0; kk < 2; ++kk)
    aF[kk] = *(const bf16x8*)(fgb + (size_t)(w * 16 + l15) * 128 + kk * 32 + l4 * 8);
#pragma unroll
  for (int dj = 0; dj < 2; ++dj)
#pragma unroll
    for (int k4 = 0; k4 < 4; ++k4)
      bV[dj][k4] = *(const bf16x8*)(vb + (size_t)(w * 32 + dj * 16 + l15) * NPIX + k4 * 32 + l4 * 8);

  f32x4 accO[4][2] = {};
  float lsum[4] = {0.f, 0.f, 0.f, 0.f};

  for (int t = 0; t < 32; ++t) {
    const int mn = ((t + 1) * 128) & (NPIX - 1);  // next m-tile (wraps on last iter)
    const int bufi = t & 1;
    // ---- QK^T (swapped): S^T[m][q], this wave's 16-m slice, all 64 q ----
    f32x4 s[4];
#pragma unroll
    for (int qt = 0; qt < 4; ++qt) {
      s[qt] = (f32x4){0.f, 0.f, 0.f, 0.f};
#pragma unroll
      for (int kk = 0; kk < 2; ++kk)
        s[qt] = __builtin_amdgcn_mfma_f32_16x16x32_bf16(aF[kk], bG[qt][kk], s[qt], 0, 0, 0);
    }
    // prefetch next aF
    bf16x8 aFn[2];
#pragma unroll
    for (int kk = 0; kk < 2; ++kk)
      aFn[kk] = *(const bf16x8*)(fgb + (size_t)(mn + w * 16 + l15) * 128 + kk * 32 + l4 * 8);
    // exp + pack pairs + write PsT[q][m]
#pragma unroll
    for (int qt = 0; qt < 4; ++qt) {
      float p0 = __expf(s[qt][0]), p1 = __expf(s[qt][1]);
      float p2 = __expf(s[qt][2]), p3 = __expf(s[qt][3]);
      lsum[qt] += (p0 + p1) + (p2 + p3);
      union { __bf16 h[2]; uint u; } w0, w1;
      w0.h[0] = (__bf16)p0; w0.h[1] = (__bf16)p1;
      w1.h[0] = (__bf16)p2; w1.h[1] = (__bf16)p3;
      *(uint*)(&PsT[bufi][qt * 16 + l15][w * 16 + l4 * 4]) = w0.u;
      *(uint*)(&PsT[bufi][qt * 16 + l15][w * 16 + l4 * 4 + 2]) = w1.u;
    }
    RAW_BARRIER();  // PsT ready; vmcnt NOT drained (prefetches stay in flight)
    // ---- PV: O[q][d-slice], P from LDS, V from regs ----
#pragma unroll
    for (int qt = 0; qt < 4; ++qt) {
      bf16x8 aP[4];
#pragma unroll
      for (int k4 = 0; k4 < 4; ++k4)
        aP[k4] = *(const bf16x8*)(&PsT[bufi][qt * 16 + l15][k4 * 32 + l4 * 8]);
#pragma unroll
      for (int dj = 0; dj < 2; ++dj)
#pragma unroll
        for (int k4 = 0; k4 < 4; ++k4)
          accO[qt][dj] = __builtin_amdgcn_mfma_f32_16x16x32_bf16(aP[k4], bV[dj][k4], accO[qt][dj], 0, 0, 0);
    }
    // prefetch next bV
#pragma unroll
    for (int dj = 0; dj < 2; ++dj)
#pragma unroll
      for (int k4 = 0; k4 < 4; ++k4)
        bV[dj][k4] = *(const bf16x8*)(vb + (size_t)(w * 32 + dj * 16 + l15) * NPIX + mn + k4 * 32 + l4 * 8);
    aF[0] = aFn[0]; aF[1] = aFn[1];
  }

  // ---- denominators: reduce lsum over l4 groups, then over waves via LDS ----
#pragma unroll
  for (int qt = 0; qt < 4; ++qt) {
    float v = lsum[qt];
    v += __shfl_xor(v, 16); v += __shfl_xor(v, 32);
    lsum[qt] = v;
  }
  if (l4 == 0) {
#pragma unroll
    for (int qt = 0; qt < 4; ++qt) Lp[w][qt * 16 + l15] = lsum[qt];
  }
  __syncthreads();
  float inv[4][4];
#pragma unroll
  for (int qt = 0; qt < 4; ++qt)
#pragma unroll
    for (int r = 0; r < 4; ++r) {
      int q = qt * 16 + l4 * 4 + r;
      float lt = 0.f;
#pragma unroll
      for (int ww = 0; ww < 8; ++ww) lt += Lp[ww][q];
      inv[qt][r] = 1.0f / lt;
    }
  __bf16* ob = obuf + ((size_t)b * NPIX + q0) * D2;
#pragma unroll
  for (int qt = 0; qt < 4; ++qt)
#pragma unroll
    for (int dj = 0; dj < 2; ++dj)
#pragma unroll
      for (int r = 0; r < 4; ++r)
        ob[(size_t)(qt * 16 + l4 * 4 + r) * D2 + w * 32 + dj * 16 + l15] =
            (__bf16)(accO[qt][dj][r] * inv[qt][r]);
}

// ---------- launch ----------
extern "C" void kernel_launch(void* const* d_in, const int* in_sizes, int n_in,
                              void* d_out, int out_size, void* d_ws, size_t ws_size,
                              hipStream_t stream) {
  const float* x = (const float*)d_in[0];
  const float* wf = (const float*)d_in[1];
  const float* bf_ = (const float*)d_in[2];
  const float* wg = (const float*)d_in[3];
  const float* bg_ = (const float*)d_in[4];
  const float* wh = (const float*)d_in[5];
  const float* bh_ = (const float*)d_in[6];
  const float* wo = (const float*)d_in[7];
  const float* bo = (const float*)d_in[8];
  const float* gamma = (const float*)d_in[9];
  const float* wc = (const float*)d_in[10];
  const float* bc = (const float*)d_in[11];
  const float* bns = (const float*)d_in[12];
  const float* bnb = (const float*)d_in[13];
  const float* bnm = (const float*)d_in[14];
  const float* bnv = (const float*)d_in[15];
  (void)in_sizes; (void)n_in; (void)out_size; (void)ws_size;

  char* ws = (char*)d_ws;
  __bf16* xb     = (__bf16*)(ws + 0);          // 16384*512*2  = 16,777,216
  __bf16* fg     = (__bf16*)(ws + 16777216);   // 16384*128*2  =  4,194,304
  __bf16* hvT    = (__bf16*)(ws + 20971520);   // 4*256*4096*2 =  8,388,608
  __bf16* obuf   = (__bf16*)(ws + 29360128);   // 16384*256*2  =  8,388,608
  __bf16* WfghT  = (__bf16*)(ws + 37748736);   // 384*512*2
  float*  bias384= (float*) (ws + 38141952);   // 384*4
  float*  Wow    = (float*) (ws + 38143488);   // 256*512*4
  __bf16* WcatT  = (__bf16*)(ws + 38667776);   // 512*768*2
  float*  biasF  = (float*) (ws + 39454208);   // 512*4
  float* out = (float*)d_out;

  hipLaunchKernelGGL(k_cvt, dim3(8192), dim3(256), 0, stream, x, xb, 2097152);
  hipLaunchKernelGGL(kp_wfgh, dim3(768), dim3(256), 0, stream, wf, wg, wh, WfghT);
  hipLaunchKernelGGL(kp_bias384, dim3(3), dim3(128), 0, stream, bf_, bg_, bh_, bias384);
  hipLaunchKernelGGL(kp_wow, dim3(512), dim3(256), 0, stream, wo, wc, Wow);
  hipLaunchKernelGGL(kp_wcat, dim3(1536), dim3(256), 0, stream, Wow, wc, gamma, bns, bnv, WcatT);
  hipLaunchKernelGGL(kp_biasF, dim3(2), dim3(256), 0, stream, bo, wc, bc, gamma, bns, bnb, bnm, bnv, biasF);
  hipLaunchKernelGGL((k_gemm<512, 384, 0>), dim3(128, 6), dim3(256), 0, stream,
                     xb, 512, 512, xb, 512, WfghT, bias384, (void*)fg, (void*)hvT);
  hipLaunchKernelGGL(k_attn, dim3(256), dim3(512), 0, stream, fg, hvT, obuf);
  hipLaunchKernelGGL((k_gemm<768, 512, 1>), dim3(128, 8), dim3(256), 0, stream,
                     obuf, 256, 256, xb, 512, WcatT, biasF, (void*)out, nullptr);
}